// Round 1
// baseline (41.978 us; speedup 1.0000x reference)
//
#include <hip/hip_runtime.h>
#include <stdint.h>

typedef _Float16 h2 __attribute__((ext_vector_type(2)));

#define HH 256
#define WW 256
#define CF 32
#define RAD 6
#define DD 13
#define TW 64
#define TH 8
#define PXN 4
#define NROWS (TH + 2*RAD)     // 20
#define NCOLS (TW + 16)        // 80
#define NC2 (CF/2)             // 16

union HU { uint32_t u; h2 h; };

__device__ __forceinline__ h2 bch2(uint32_t u){ HU x; x.u = u; return x.h; }
__device__ __forceinline__ uint32_t packh2(float a, float b){
    HU x; x.h[0] = (_Float16)a; x.h[1] = (_Float16)b; return x.u;
}

__global__ __launch_bounds__(256, 1)
void corr_recon(const float* __restrict__ ft, const float* __restrict__ fr,
                const float* __restrict__ img, float* __restrict__ out)
{
    __shared__ uint32_t fr_lds[NROWS * NC2 * NCOLS];   // 20*16*80*4 = 102400 B
    __shared__ float img_lds[NROWS * NCOLS];           // 6400 B

    const int bid = blockIdx.x;
    const int b0  = bid >> 7;          // 128 tiles per batch
    const int rb  = bid & 127;
    const int ty0 = (rb >> 2) * TH;    // 32 row-tiles
    const int tx0 = (rb & 3) * TW;     // 4 col-tiles

    const int tid  = threadIdx.x;
    const int lane = tid & 63;
    const int hf   = lane >> 5;                        // dy-parity half
    const int slot = ((tid >> 6) << 5) | (lane & 31);  // 128 pixel-slots
    const int sx   = slot & 15;
    const int sy   = slot >> 4;
    const int x0   = sx * PXN;

    const float* frb = fr  + (size_t)b0 * CF * HH * WW;
    const float* ftb = ft  + (size_t)b0 * CF * HH * WW;
    const float* imb = img + (size_t)b0 * HH * WW;

    // ---- stage fr tile as packed fp16 channel-pairs ----
    for (int t = tid; t < NROWS * NC2 * (NCOLS/4); t += 256) {
        const int cg = t % (NCOLS/4);
        const int rc = t / (NCOLS/4);
        const int c2 = rc % NC2;
        const int rr = rc / NC2;
        const int gy = ty0 - RAD + rr;
        const int gx = tx0 - 8 + cg*4;
        float a[4] = {0,0,0,0}, b[4] = {0,0,0,0};
        if (gy >= 0 && gy < HH) {
            const float* p0 = frb + ((size_t)(2*c2) * HH + gy) * WW + gx;
            const float* p1 = p0 + (size_t)HH * WW;
            if (gx >= 0 && gx + 3 < WW) {
                float4 va = *(const float4*)p0;
                float4 vb = *(const float4*)p1;
                a[0]=va.x; a[1]=va.y; a[2]=va.z; a[3]=va.w;
                b[0]=vb.x; b[1]=vb.y; b[2]=vb.z; b[3]=vb.w;
            } else {
                #pragma unroll
                for (int j = 0; j < 4; ++j) {
                    int x = gx + j;
                    if (x >= 0 && x < WW) { a[j] = p0[j]; b[j] = p1[j]; }
                }
            }
        }
        uint4 wv;
        wv.x = packh2(a[0], b[0]); wv.y = packh2(a[1], b[1]);
        wv.z = packh2(a[2], b[2]); wv.w = packh2(a[3], b[3]);
        *(uint4*)&fr_lds[(rr*NC2 + c2)*NCOLS + cg*4] = wv;
    }
    // ---- stage img tile (fp32) ----
    for (int t = tid; t < NROWS * (NCOLS/4); t += 256) {
        const int cg = t % (NCOLS/4);
        const int rr = t / (NCOLS/4);
        const int gy = ty0 - RAD + rr;
        const int gx = tx0 - 8 + cg*4;
        float v[4] = {0,0,0,0};
        if (gy >= 0 && gy < HH) {
            const float* p = imb + (size_t)gy * WW + gx;
            if (gx >= 0 && gx + 3 < WW) {
                float4 t4 = *(const float4*)p;
                v[0]=t4.x; v[1]=t4.y; v[2]=t4.z; v[3]=t4.w;
            } else {
                #pragma unroll
                for (int j = 0; j < 4; ++j) {
                    int x = gx + j;
                    if (x >= 0 && x < WW) v[j] = p[j];
                }
            }
        }
        float4 f4; f4.x=v[0]; f4.y=v[1]; f4.z=v[2]; f4.w=v[3];
        *(float4*)&img_lds[rr*NCOLS + cg*4] = f4;
    }

    // ---- ft -> registers as fp16 pairs (loaded once, reused for all 169 d) ----
    h2 ftv[PXN][NC2];
    {
        const float* p = ftb + (size_t)(ty0 + sy) * WW + (tx0 + x0);
        #pragma unroll
        for (int c2 = 0; c2 < NC2; ++c2) {
            float4 va = *(const float4*)(p + (size_t)(2*c2)   * HH * WW);
            float4 vb = *(const float4*)(p + (size_t)(2*c2+1) * HH * WW);
            ftv[0][c2][0]=(_Float16)va.x; ftv[0][c2][1]=(_Float16)vb.x;
            ftv[1][c2][0]=(_Float16)va.y; ftv[1][c2][1]=(_Float16)vb.y;
            ftv[2][c2][0]=(_Float16)va.z; ftv[2][c2][1]=(_Float16)vb.z;
            ftv[3][c2][0]=(_Float16)va.w; ftv[3][c2][1]=(_Float16)vb.w;
        }
    }

    __syncthreads();

    float l[PXN]  = {0,0,0,0};
    float ac[PXN] = {0,0,0,0};

    // each dy-parity half sweeps its own dy values over the shared static tile
    for (int dy = hf; dy < DD; dy += 2) {
        const int row = sy + dy;   // LDS row index (gy = ty0-6+sy+dy)
        float corr[PXN][DD];
        #pragma unroll
        for (int px = 0; px < PXN; ++px)
            #pragma unroll
            for (int dx = 0; dx < DD; ++dx) corr[px][dx] = 0.f;

        #pragma unroll
        for (int c2 = 0; c2 < NC2; ++c2) {
            const uint32_t* bp = &fr_lds[(row*NC2 + c2)*NCOLS + x0];
            uint4 q0 = *(const uint4*)(bp + 0);
            uint4 q1 = *(const uint4*)(bp + 4);
            uint4 q2 = *(const uint4*)(bp + 8);
            uint4 q3 = *(const uint4*)(bp + 12);
            uint4 q4 = *(const uint4*)(bp + 16);
            uint32_t w[20] = {q0.x,q0.y,q0.z,q0.w, q1.x,q1.y,q1.z,q1.w,
                              q2.x,q2.y,q2.z,q2.w, q3.x,q3.y,q3.z,q3.w,
                              q4.x,q4.y,q4.z,q4.w};
            #pragma unroll
            for (int px = 0; px < PXN; ++px)
                #pragma unroll
                for (int dx = 0; dx < DD; ++dx)
                    corr[px][dx] = __builtin_amdgcn_fdot2(
                        ftv[px][c2], bch2(w[px+dx+2]), corr[px][dx], false);
        }

        const float* ip = &img_lds[row*NCOLS + x0];
        float4 i0 = *(const float4*)(ip + 0);
        float4 i1 = *(const float4*)(ip + 4);
        float4 i2 = *(const float4*)(ip + 8);
        float4 i3 = *(const float4*)(ip + 12);
        float4 i4 = *(const float4*)(ip + 16);
        float iw[20] = {i0.x,i0.y,i0.z,i0.w, i1.x,i1.y,i1.z,i1.w,
                        i2.x,i2.y,i2.z,i2.w, i3.x,i3.y,i3.z,i3.w,
                        i4.x,i4.y,i4.z,i4.w};
        // online (no-max) softmax accumulate: |corr| <= ~35 so exp stays in fp32 range
        #pragma unroll
        for (int px = 0; px < PXN; ++px)
            #pragma unroll
            for (int dx = 0; dx < DD; ++dx) {
                float e = __expf(corr[px][dx]);
                l[px]  += e;
                ac[px] += e * iw[px+dx+2];
            }
    }

    // merge the two dy-parity halves (partner lane = lane ^ 32)
    #pragma unroll
    for (int px = 0; px < PXN; ++px) {
        l[px]  += __shfl_xor(l[px], 32);
        ac[px] += __shfl_xor(ac[px], 32);
    }
    if (hf == 0) {
        float4 o;
        o.x = ac[0]/l[0]; o.y = ac[1]/l[1]; o.z = ac[2]/l[2]; o.w = ac[3]/l[3];
        *(float4*)&out[((size_t)b0 * HH + (ty0 + sy)) * WW + (tx0 + x0)] = o;
    }
}

extern "C" void kernel_launch(void* const* d_in, const int* in_sizes, int n_in,
                              void* d_out, int out_size, void* d_ws, size_t ws_size,
                              hipStream_t stream)
{
    const float* ft  = (const float*)d_in[0];  // feats_t  (2,32,256,256) f32
    const float* fr  = (const float*)d_in[1];  // feats_r  (2,32,256,256) f32
    const float* img = (const float*)d_in[2];  // img_r    (2,1,256,256)  f32
    float* out = (float*)d_out;                // (2,1,256,256) f32
    (void)in_sizes; (void)n_in; (void)out_size; (void)d_ws; (void)ws_size;
    corr_recon<<<256, 256, 0, stream>>>(ft, fr, img, out);
}